// Round 1
// baseline (30532.959 us; speedup 1.0000x reference)
//
#include <hip/hip_runtime.h>

typedef short short8 __attribute__((ext_vector_type(8)));
typedef short short4v __attribute__((ext_vector_type(4)));
typedef float f32x4 __attribute__((ext_vector_type(4)));

#define B_STEPS 1024
#define ROWS_PER_BLK 16
#define GSTRIDE 1033  // padded f32 stride for gates LDS (breaks 4-way bank conflict)

__device__ __forceinline__ unsigned short f2bf(float f) {
  unsigned u = __builtin_bit_cast(unsigned, f);
  u += 0x7fffu + ((u >> 16) & 1u);  // RNE
  return (unsigned short)(u >> 16);
}

__device__ __forceinline__ float sigm_f(float x) {
  return __builtin_amdgcn_rcpf(1.0f + __expf(-x));
}
__device__ __forceinline__ float tanh_fast(float x) {
  // tanh(x) = 2*sigmoid(2x) - 1 ; saturates correctly at +-inf
  return 2.0f * __builtin_amdgcn_rcpf(1.0f + __expf(-2.0f * x)) - 1.0f;
}

// Bt[n][k] bf16, n in [0,1024) gate-col, k in [0,512) = [W_ih rows | W_hh rows]
__global__ __launch_bounds__(256) void prep_w_kernel(
    const float* __restrict__ Wih, const float* __restrict__ Whh,
    unsigned short* __restrict__ Bt) {
  int idx = blockIdx.x * 256 + threadIdx.x;  // 0 .. 524287 = n*512 + k
  int n = idx >> 9;
  int k = idx & 511;
  float v = (k < 256) ? Wih[k * 1024 + n] : Whh[(k - 256) * 1024 + n];
  Bt[idx] = f2bf(v);
}

// 16 blocks x 1024 threads. Block b owns sequence-rows [16b,16b+16) for all 1024 steps.
// A_lds = [x_t | h] (16 x 512 bf16, XOR-swizzled rows); B streamed from L2 each step.
__global__ __launch_bounds__(1024) void lstm_seq_kernel(
    const float* __restrict__ x, const float* __restrict__ bias,
    const unsigned short* __restrict__ Bt, float* __restrict__ out) {
  __shared__ __align__(16) unsigned char Abuf[ROWS_PER_BLK * 1024];  // 16 KB
  __shared__ float gbuf[ROWS_PER_BLK * GSTRIDE];                     // ~66 KB

  const int tid = threadIdx.x;
  const int r0 = blockIdx.x * ROWS_PER_BLK;

  // zero A (h-part must start at h0 = 0)
  {
    short8 z = 0;
    *(short8*)(Abuf + tid * 16) = z;
  }

  // ---- update-phase mapping: thread -> (col, 4 rows) ----
  const int col = tid & 255;
  const int rg = tid >> 8;  // 0..3 -> rows rg*4 .. rg*4+3
  float c[4] = {0.f, 0.f, 0.f, 0.f};
  const float bi = bias[col];
  const float bf_ = bias[col + 256];
  const float bg_ = bias[col + 512];
  const float bo_ = bias[col + 768];

  // ---- GEMM mapping: wave owns gate-cols [wave*64, wave*64+64) ----
  const int lane = tid & 63;
  const int wave = tid >> 6;
  const int lm = lane & 15;            // A row / B col within 16x16 tile
  const int lkb = (lane >> 4) * 16;    // byte offset of this lane-group's k chunk
  const int aswz = (lm & 7) << 4;
  const unsigned char* Arow = Abuf + lm * 1024;
  const unsigned short* Bw = Bt + (size_t)(wave * 64 + lm) * 512 + (lane >> 4) * 8;

  // ---- x staging mapping: wave w loads row w (256 f32 -> bf16) ----
  const int sxrow = tid >> 6;
  const int sxc = (tid & 63) * 4;
  const float* xp = x + (size_t)(r0 + sxrow) * 256 + sxc;
  unsigned char* Asx = Abuf + sxrow * 1024 + ((sxc * 2) ^ ((sxrow & 7) << 4));

  for (int t = 0; t < B_STEPS; ++t) {
    // phase U: stage x_t (A k=0..255) + apply gates(t-1) -> c,h, out, A k=256..511
    {
      const float* p = xp + (size_t)t * 65536;
      short4v s;
      s[0] = (short)f2bf(p[0]);
      s[1] = (short)f2bf(p[1]);
      s[2] = (short)f2bf(p[2]);
      s[3] = (short)f2bf(p[3]);
      *(short4v*)Asx = s;
    }
    if (t > 0) {
      const int tprev = t - 1;
#pragma unroll
      for (int j = 0; j < 4; ++j) {
        const int r = rg * 4 + j;
        const float* grow = gbuf + r * GSTRIDE + col;
        float gi = grow[0] + bi;
        float gf = grow[256] + bf_;
        float gg = grow[512] + bg_;
        float go = grow[768] + bo_;
        float iv = sigm_f(gi);
        float fv = sigm_f(gf);
        float gv = tanh_fast(gg);
        float ov = sigm_f(go);
        float cj = fv * c[j] + iv * gv;
        c[j] = cj;
        float h = ov * tanh_fast(cj);
        out[(size_t)tprev * 65536 + (size_t)(r0 + r) * 256 + col] = h;
        *(unsigned short*)(Abuf + r * 1024 + ((512 + 2 * col) ^ ((r & 7) << 4))) =
            f2bf(h);
      }
    }
    __syncthreads();

    // phase G: gates(t) = A @ B   (16 x 512) @ (512 x 64-per-wave)
    f32x4 acc[4];
#pragma unroll
    for (int nt = 0; nt < 4; ++nt) acc[nt] = (f32x4){0.f, 0.f, 0.f, 0.f};

#pragma unroll 2
    for (int kt = 0; kt < 16; ++kt) {
      short8 a = *(const short8*)(Arow + ((kt * 64 + lkb) ^ aswz));
      const unsigned short* bp = Bw + kt * 32;
#pragma unroll
      for (int nt = 0; nt < 4; ++nt) {
        short8 b = *(const short8*)(bp + nt * (16 * 512));
        acc[nt] = __builtin_amdgcn_mfma_f32_16x16x32_bf16(a, b, acc[nt], 0, 0, 0);
      }
    }

    // D layout (m89-verified): col = lane&15, row = (lane>>4)*4 + reg
    const int mb = (lane >> 4) * 4;
#pragma unroll
    for (int nt = 0; nt < 4; ++nt) {
      const int n = wave * 64 + nt * 16 + lm;
#pragma unroll
      for (int i = 0; i < 4; ++i) gbuf[(mb + i) * GSTRIDE + n] = acc[nt][i];
    }
    __syncthreads();
  }

  // final update (t = 1023) + h_t / c_t tails
  {
    const int tprev = B_STEPS - 1;
#pragma unroll
    for (int j = 0; j < 4; ++j) {
      const int r = rg * 4 + j;
      const float* grow = gbuf + r * GSTRIDE + col;
      float gi = grow[0] + bi;
      float gf = grow[256] + bf_;
      float gg = grow[512] + bg_;
      float go = grow[768] + bo_;
      float iv = sigm_f(gi);
      float fv = sigm_f(gf);
      float gv = tanh_fast(gg);
      float ov = sigm_f(go);
      float cj = fv * c[j] + iv * gv;
      float h = ov * tanh_fast(cj);
      out[(size_t)tprev * 65536 + (size_t)(r0 + r) * 256 + col] = h;
      out[(size_t)67108864 + (size_t)(r0 + r) * 256 + col] = h;
      out[(size_t)67108864 + 65536 + (size_t)(r0 + r) * 256 + col] = cj;
    }
  }
}

extern "C" void kernel_launch(void* const* d_in, const int* in_sizes, int n_in,
                              void* d_out, int out_size, void* d_ws, size_t ws_size,
                              hipStream_t stream) {
  const float* x = (const float*)d_in[0];
  const float* Wih = (const float*)d_in[1];
  const float* Whh = (const float*)d_in[2];
  const float* bias = (const float*)d_in[3];
  float* out = (float*)d_out;
  unsigned short* Bt = (unsigned short*)d_ws;  // 1024 x 512 bf16 = 1 MB

  prep_w_kernel<<<2048, 256, 0, stream>>>(Wih, Whh, Bt);
  lstm_seq_kernel<<<16, 1024, 0, stream>>>(x, bias, Bt, out);
}